// Round 2
// baseline (106.059 us; speedup 1.0000x reference)
//
#include <hip/hip_runtime.h>

// SKA involution-style conv:
// out[b, i*32+g, h, w] = sum_{di,dj} x[b, i*32+g, h+di-1, w+dj-1] * w[b, g, 3*di+dj, h, w]
// x: (8,256,56,56) f32, w: (8,32,9,56,56) f32, out: (8,256,56,56) f32
//
// Blocking: each thread computes 4 consecutive pixels (along w) x 2 output rows
// x 4 channels = 32 outputs. Weights (18 float4) loaded once per task, reused
// across the 4 channels. Boundary conditions are folded into the weights
// (zeroed taps), so x loads are unpredicated with clamped addresses.

#define W_DIM 56
#define H_DIM 56
#define HW 3136

__global__ __launch_bounds__(256) void SKA_20950850470021_kernel(
    const float* __restrict__ x, const float* __restrict__ wt,
    float* __restrict__ out) {
  // Task decomposition: t = ((plane*2 + i0)*28 + rp)*14 + ct
  const int t  = blockIdx.x * 256 + threadIdx.x;   // 0 .. 200703
  const int ct = t % 14;                            // column task -> wp = ct*4
  const int t2 = t / 14;
  const int rp = t2 % 28;                           // row pair -> h0 = rp*2
  const int t3 = t2 / 28;
  const int i0 = t3 & 1;                            // channel half (0/1)
  const int pg = t3 >> 1;                           // plane: b*32 + g
  const int b  = pg >> 5;
  const int g  = pg & 31;

  const int wp = ct * 4;
  const int h0 = rp * 2;

  // ---- load 18 weight float4s: wk[d][k], d = output row 0/1, k = tap ----
  const float* wbase = wt + (size_t)pg * 9 * HW + h0 * W_DIM + wp;
  float4 wk[2][9];
#pragma unroll
  for (int k = 0; k < 9; ++k) {
    wk[0][k] = *(const float4*)(wbase + (size_t)k * HW);
    wk[1][k] = *(const float4*)(wbase + (size_t)k * HW + W_DIM);
  }

  // ---- fold boundaries into weights (branch-free) ----
  // top: output row h0==0 -> taps di=0 (k=0..2) read row -1
  const float mtop = (h0 == 0) ? 0.f : 1.f;
  // bottom: output row h0+1==55 -> taps di=2 (k=6..8) read row 56
  const float mbot = (h0 == 54) ? 0.f : 1.f;
#pragma unroll
  for (int k = 0; k < 3; ++k) {
    wk[0][k].x *= mtop; wk[0][k].y *= mtop; wk[0][k].z *= mtop; wk[0][k].w *= mtop;
    wk[1][k + 6].x *= mbot; wk[1][k + 6].y *= mbot; wk[1][k + 6].z *= mbot; wk[1][k + 6].w *= mbot;
  }
  // left: pixel t=0 with dj=0 (k=0,3,6) reads col wp-1
  const float mleft = (wp == 0) ? 0.f : 1.f;
  // right: pixel t=3 with dj=2 (k=2,5,8) reads col wp+4
  const float mright = (wp == 52) ? 0.f : 1.f;
#pragma unroll
  for (int d = 0; d < 2; ++d)
#pragma unroll
    for (int di = 0; di < 3; ++di) {
      wk[d][di * 3 + 0].x *= mleft;
      wk[d][di * 3 + 2].w *= mright;
    }

  // ---- x row addressing (clamped; garbage reads are multiplied by 0) ----
  int rh[4];
#pragma unroll
  for (int r = 0; r < 4; ++r) {
    int hh = h0 - 1 + r;
    hh = hh < 0 ? 0 : (hh > 55 ? 55 : hh);
    rh[r] = hh * W_DIM;
  }
  const int cs0 = (wp == 0) ? 0 : wp - 1;
  const int cs5 = (wp == 52) ? 55 : wp + 4;

  const float* xplane = x + ((size_t)b * 256 + (size_t)i0 * 4 * 32 + g) * HW;
  float*       oplane = out + ((size_t)b * 256 + (size_t)i0 * 4 * 32 + g) * HW;
  const int    opix   = h0 * W_DIM + wp;

#pragma unroll 2
  for (int j = 0; j < 4; ++j) {
    const float* xc = xplane + (size_t)(j * 32) * HW;

    // 4 rows x 6 cols of x: xr[r][0..5] = x[row, wp-1 .. wp+4]
    float xr[4][6];
#pragma unroll
    for (int r = 0; r < 4; ++r) {
      const float* rowp = xc + rh[r];
      xr[r][0] = rowp[cs0];
      const float4 m = *(const float4*)(rowp + wp);
      xr[r][1] = m.x; xr[r][2] = m.y; xr[r][3] = m.z; xr[r][4] = m.w;
      xr[r][5] = rowp[cs5];
    }

    float4 a0 = make_float4(0.f, 0.f, 0.f, 0.f);
    float4 a1 = make_float4(0.f, 0.f, 0.f, 0.f);
#pragma unroll
    for (int di = 0; di < 3; ++di)
#pragma unroll
      for (int dj = 0; dj < 3; ++dj) {
        const float4 W0 = wk[0][di * 3 + dj];
        const float4 W1 = wk[1][di * 3 + dj];
        a0.x = fmaf(xr[di][dj + 0], W0.x, a0.x);
        a0.y = fmaf(xr[di][dj + 1], W0.y, a0.y);
        a0.z = fmaf(xr[di][dj + 2], W0.z, a0.z);
        a0.w = fmaf(xr[di][dj + 3], W0.w, a0.w);
        a1.x = fmaf(xr[di + 1][dj + 0], W1.x, a1.x);
        a1.y = fmaf(xr[di + 1][dj + 1], W1.y, a1.y);
        a1.z = fmaf(xr[di + 1][dj + 2], W1.z, a1.z);
        a1.w = fmaf(xr[di + 1][dj + 3], W1.w, a1.w);
      }

    float* op = oplane + (size_t)(j * 32) * HW + opix;
    *(float4*)op = a0;
    *(float4*)(op + W_DIM) = a1;
  }
}

extern "C" void kernel_launch(void* const* d_in, const int* in_sizes, int n_in,
                              void* d_out, int out_size, void* d_ws, size_t ws_size,
                              hipStream_t stream) {
  const float* x  = (const float*)d_in[0];
  const float* wt = (const float*)d_in[1];
  float* out = (float*)d_out;

  // 200704 tasks = 784 blocks x 256 threads
  SKA_20950850470021_kernel<<<dim3(784), dim3(256), 0, stream>>>(x, wt, out);
}

// Round 3
// 98.003 us; speedup vs baseline: 1.0822x; 1.0822x over previous
//
#include <hip/hip_runtime.h>

// SKA involution-style conv:
// out[b, i*32+g, h, w] = sum_{di,dj} x[b, i*32+g, h+di-1, w+dj-1] * w[b, g, 3*di+dj, h, w]
// x: (8,256,56,56) f32, w: (8,32,9,56,56) f32, out: (8,256,56,56) f32
//
// R3: LDS-tiled. One block per (b,g) plane x 14-row band. The 8-channel x tile
// (16 rows incl halo x 58 cols, zero-padded) is staged into LDS once, so:
//   - w is read exactly once from global (29 MB unique)
//   - x is read 1.14x unique (band halo only)
//   - all boundary handling folds into the zero-padded LDS halo (branch-free compute)
// Each compute thread owns one (output row, 4-col quad) and produces all 8 channels.

#define HW 3136
#define W_DIM 56
#define LDS_STRIDE 60   // floats per LDS row; 60*4=240 B keeps row bases 16B-aligned
#define BAND 14
#define XROWS 16        // BAND + 2 halo rows

__global__ __launch_bounds__(256) void SKA_20950850470021_kernel(
    const float* __restrict__ x, const float* __restrict__ wt,
    float* __restrict__ out) {
  __shared__ float lx[8 * XROWS * LDS_STRIDE];   // 30720 B

  const int pg   = blockIdx.x;    // b*32 + g
  const int band = blockIdx.y;    // 0..3
  const int h0   = band * BAND;
  const int b    = pg >> 5;
  const int g    = pg & 31;
  const int tid  = threadIdx.x;

  // --- zero halo columns (LDS col 0 and 57) for every (ch,row): 256 cells, 1/thread
  {
    const int ch  = tid >> 5;
    const int r   = (tid >> 1) & 15;
    const int col = (tid & 1) ? 57 : 0;
    lx[(ch * XROWS + r) * LDS_STRIDE + col] = 0.f;
  }

  // --- stage x rows h0-1 .. h0+14 into LDS cols 1..56 (zeros for out-of-plane rows)
  // 8 ch x 16 rows x 14 float4 = 1792 units = 256 threads x 7 iters, coalesced in j.
  const float* xg = x + ((size_t)b * 256 + g) * HW;   // + ch*32*HW per channel
  for (int it = 0; it < 7; ++it) {
    const int idx = tid + it * 256;     // 0..1791
    const int j   = idx % 14;           // col quad
    const int u   = idx / 14;           // 0..127 -> (ch, r)
    const int ch  = u >> 4;
    const int r   = u & 15;
    const int gr  = h0 + r - 1;
    float4 v = make_float4(0.f, 0.f, 0.f, 0.f);
    if ((unsigned)gr < 56u)
      v = *(const float4*)(xg + (size_t)ch * 32 * HW + gr * W_DIM + 4 * j);
    float* d = &lx[(ch * XROWS + r) * LDS_STRIDE + 1 + 4 * j];
    d[0] = v.x; d[1] = v.y; d[2] = v.z; d[3] = v.w;
  }

  __syncthreads();

  // --- compute: thread = (output row r in band, col quad q); 196 active threads
  if (tid >= BAND * 14) return;
  const int q  = tid % 14;
  const int r  = tid / 14;
  const int gr = h0 + r;          // global output row
  const int c0 = 4 * q;

  // 9 per-pixel weight float4s, read exactly once, reused across 8 channels
  const float* wb = wt + (size_t)pg * 9 * HW + gr * W_DIM + c0;
  float4 wk[9];
#pragma unroll
  for (int k = 0; k < 9; ++k) wk[k] = *(const float4*)(wb + (size_t)k * HW);

  float* ob = out + ((size_t)b * 256 + g) * HW + gr * W_DIM + c0;

#pragma unroll
  for (int ch = 0; ch < 8; ++ch) {
    // x rows gr-1..gr+1 = LDS rows r..r+2; x cols c0-1..c0+4 = LDS cols 4q..4q+5
    // (b128 at 4q is 16B-aligned; b64 at 4q+4 is 8B-aligned)
    float xr[3][6];
#pragma unroll
    for (int dr = 0; dr < 3; ++dr) {
      const float* p = &lx[(ch * XROWS + r + dr) * LDS_STRIDE + 4 * q];
      const float4 a = *(const float4*)p;
      const float2 bb = *(const float2*)(p + 4);
      xr[dr][0] = a.x; xr[dr][1] = a.y; xr[dr][2] = a.z; xr[dr][3] = a.w;
      xr[dr][4] = bb.x; xr[dr][5] = bb.y;
    }

    float4 acc = make_float4(0.f, 0.f, 0.f, 0.f);
#pragma unroll
    for (int di = 0; di < 3; ++di)
#pragma unroll
      for (int dj = 0; dj < 3; ++dj) {
        const float4 W = wk[di * 3 + dj];
        acc.x = fmaf(xr[di][dj + 0], W.x, acc.x);
        acc.y = fmaf(xr[di][dj + 1], W.y, acc.y);
        acc.z = fmaf(xr[di][dj + 2], W.z, acc.z);
        acc.w = fmaf(xr[di][dj + 3], W.w, acc.w);
      }
    *(float4*)(ob + (size_t)ch * 32 * HW) = acc;
  }
}

extern "C" void kernel_launch(void* const* d_in, const int* in_sizes, int n_in,
                              void* d_out, int out_size, void* d_ws, size_t ws_size,
                              hipStream_t stream) {
  const float* x  = (const float*)d_in[0];
  const float* wt = (const float*)d_in[1];
  float* out = (float*)d_out;

  dim3 grid(256, 4);   // (b*32+g) x row-band
  SKA_20950850470021_kernel<<<grid, 256, 0, stream>>>(x, wt, out);
}